// Round 1
// baseline (3458.611 us; speedup 1.0000x reference)
//
#include <hip/hip_runtime.h>
#include <cstddef>
#include <cstdint>

// Problem dims (fixed by setup_inputs): B=4, L=2048, D=1024, H=16, dh=64.
#define D_MODEL 1024
#define NH      16
#define DH      64
#define BATCH   4
#define SEQ     2048
#define BL      (BATCH * SEQ)   // 8192 rows
#define BHEADS  (BATCH * NH)    // 64 (b,h) pairs
// Reference quirk: scale = 1/sqrt(batch) = 1/sqrt(4) = 0.5
#define SCALE   0.5f

// ---------------------------------------------------------------------------
// 64x64 tile, BK=16, 256 threads, 4x4 register blocking fp32 GEMM.
// HEADOUT=1: write C[m][n] to head layout [B,H,L,DH] (m=(b,l), n=(h,dh)) + bias
// HEADOUT=0: write C[m][n] to flat [M,1024] + bias
// ---------------------------------------------------------------------------
template <int HEADOUT>
__global__ __launch_bounds__(256) void gemm_proj(const float* __restrict__ A,
                                                 const float* __restrict__ W,
                                                 const float* __restrict__ bias,
                                                 float* __restrict__ out) {
  __shared__ float As[16][66];  // [k][m], padded: transposed store conflict-free
  __shared__ float Bs[16][64];  // [k][n]
  const int tid = threadIdx.x;
  const int m0 = blockIdx.y * 64;
  const int n0 = blockIdx.x * 64;
  const int ty = tid >> 4, tx = tid & 15;
  const int p = tid * 4;
  const int ar = p >> 4, ac = p & 15;   // A tile: 64 rows x 16 cols
  const int br = p >> 6, bc = p & 63;   // B tile: 16 rows x 64 cols
  float acc[4][4] = {};

  for (int k0 = 0; k0 < D_MODEL; k0 += 16) {
    float4 av = *(const float4*)&A[(size_t)(m0 + ar) * D_MODEL + k0 + ac];
    float4 bv = *(const float4*)&W[(size_t)(k0 + br) * D_MODEL + n0 + bc];
    As[ac + 0][ar] = av.x; As[ac + 1][ar] = av.y;
    As[ac + 2][ar] = av.z; As[ac + 3][ar] = av.w;
    *(float4*)&Bs[br][bc] = bv;
    __syncthreads();
#pragma unroll
    for (int kk = 0; kk < 16; ++kk) {
      float a[4], b[4];
#pragma unroll
      for (int i = 0; i < 4; ++i) a[i] = As[kk][ty * 4 + i];
#pragma unroll
      for (int j = 0; j < 4; ++j) b[j] = Bs[kk][tx * 4 + j];
#pragma unroll
      for (int i = 0; i < 4; ++i)
#pragma unroll
        for (int j = 0; j < 4; ++j) acc[i][j] += a[i] * b[j];
    }
    __syncthreads();
  }

#pragma unroll
  for (int i = 0; i < 4; ++i) {
    const int m = m0 + ty * 4 + i;
#pragma unroll
    for (int j = 0; j < 4; ++j) {
      const int n = n0 + tx * 4 + j;
      const float val = acc[i][j] + bias[n];
      if (HEADOUT) {
        const int b = m >> 11, l = m & (SEQ - 1);
        const int h = n >> 6, dh = n & 63;
        out[(((size_t)(b * NH + h) * SEQ) + l) * DH + dh] = val;
      } else {
        out[(size_t)m * D_MODEL + n] = val;
      }
    }
  }
}

// ---------------------------------------------------------------------------
// Scores: per (b,h): S = Qh(2048x64) @ Kh(2048x64)^T * SCALE  (raw, pre-softmax)
// grid (L/64, L/64, BHEADS)
// ---------------------------------------------------------------------------
__global__ __launch_bounds__(256) void gemm_scores(const float* __restrict__ Q,
                                                   const float* __restrict__ K,
                                                   float* __restrict__ S) {
  __shared__ float As[16][66];  // [k][m]
  __shared__ float Bs[16][66];  // [k][n]
  const int bh = blockIdx.z;
  const float* Qh = Q + (size_t)bh * SEQ * DH;
  const float* Kh = K + (size_t)bh * SEQ * DH;
  float* Sh = S + (size_t)bh * SEQ * SEQ;
  const int tid = threadIdx.x;
  const int m0 = blockIdx.y * 64;
  const int n0 = blockIdx.x * 64;
  const int ty = tid >> 4, tx = tid & 15;
  const int p = tid * 4;
  const int r = p >> 4, c = p & 15;  // both tiles are 64 rows x 16 cols
  float acc[4][4] = {};

  for (int k0 = 0; k0 < DH; k0 += 16) {
    float4 av = *(const float4*)&Qh[(size_t)(m0 + r) * DH + k0 + c];
    float4 bv = *(const float4*)&Kh[(size_t)(n0 + r) * DH + k0 + c];
    As[c + 0][r] = av.x; As[c + 1][r] = av.y;
    As[c + 2][r] = av.z; As[c + 3][r] = av.w;
    Bs[c + 0][r] = bv.x; Bs[c + 1][r] = bv.y;
    Bs[c + 2][r] = bv.z; Bs[c + 3][r] = bv.w;
    __syncthreads();
#pragma unroll
    for (int kk = 0; kk < 16; ++kk) {
      float a[4], b[4];
#pragma unroll
      for (int i = 0; i < 4; ++i) a[i] = As[kk][ty * 4 + i];
#pragma unroll
      for (int j = 0; j < 4; ++j) b[j] = Bs[kk][tx * 4 + j];
#pragma unroll
      for (int i = 0; i < 4; ++i)
#pragma unroll
        for (int j = 0; j < 4; ++j) acc[i][j] += a[i] * b[j];
    }
    __syncthreads();
  }

#pragma unroll
  for (int i = 0; i < 4; ++i) {
    const int m = m0 + ty * 4 + i;
#pragma unroll
    for (int j = 0; j < 4; ++j) {
      const int n = n0 + tx * 4 + j;
      Sh[(size_t)m * SEQ + n] = acc[i][j] * SCALE;
    }
  }
}

// ---------------------------------------------------------------------------
// In-place row softmax over 2048 cols; one block (256 thr) per row.
// grid = BHEADS*SEQ = 131072 blocks. This produces the attn output directly.
// ---------------------------------------------------------------------------
__global__ __launch_bounds__(256) void softmax_rows(float* __restrict__ S) {
  float* row = S + (size_t)blockIdx.x * SEQ;
  const int tid = threadIdx.x;
  float4 x0 = ((const float4*)row)[tid];
  float4 x1 = ((const float4*)row)[tid + 256];

  float m = fmaxf(fmaxf(fmaxf(x0.x, x0.y), fmaxf(x0.z, x0.w)),
                  fmaxf(fmaxf(x1.x, x1.y), fmaxf(x1.z, x1.w)));
#pragma unroll
  for (int off = 32; off; off >>= 1) m = fmaxf(m, __shfl_xor(m, off));
  __shared__ float redm[4];
  __shared__ float reds[4];
  const int wave = tid >> 6, lane = tid & 63;
  if (lane == 0) redm[wave] = m;
  __syncthreads();
  m = fmaxf(fmaxf(redm[0], redm[1]), fmaxf(redm[2], redm[3]));

  x0.x = __expf(x0.x - m); x0.y = __expf(x0.y - m);
  x0.z = __expf(x0.z - m); x0.w = __expf(x0.w - m);
  x1.x = __expf(x1.x - m); x1.y = __expf(x1.y - m);
  x1.z = __expf(x1.z - m); x1.w = __expf(x1.w - m);

  float s = x0.x + x0.y + x0.z + x0.w + x1.x + x1.y + x1.z + x1.w;
#pragma unroll
  for (int off = 32; off; off >>= 1) s += __shfl_xor(s, off);
  if (lane == 0) reds[wave] = s;
  __syncthreads();
  s = reds[0] + reds[1] + reds[2] + reds[3];

  const float inv = 1.0f / s;
  x0.x *= inv; x0.y *= inv; x0.z *= inv; x0.w *= inv;
  x1.x *= inv; x1.y *= inv; x1.z *= inv; x1.w *= inv;
  ((float4*)row)[tid] = x0;
  ((float4*)row)[tid + 256] = x1;
}

// ---------------------------------------------------------------------------
// PV: per (b,h): O = P(2048x2048) @ Vh(2048x64); write ctx in [B,L,D] layout.
// grid (L/64, BHEADS)
// ---------------------------------------------------------------------------
__global__ __launch_bounds__(256) void gemm_pv(const float* __restrict__ P,
                                               const float* __restrict__ V,
                                               float* __restrict__ ctx) {
  __shared__ float As[16][66];  // [k][m]
  __shared__ float Bs[16][64];  // [k][n]
  const int bh = blockIdx.y;
  const int b = bh >> 4, h = bh & 15;
  const float* Ph = P + (size_t)bh * SEQ * SEQ;
  const float* Vh = V + (size_t)bh * SEQ * DH;
  const int tid = threadIdx.x;
  const int m0 = blockIdx.x * 64;
  const int ty = tid >> 4, tx = tid & 15;
  const int p = tid * 4;
  const int ar = p >> 4, ac = p & 15;  // A tile: 64x16
  const int br = p >> 6, bc = p & 63;  // B tile: 16x64
  float acc[4][4] = {};

  for (int k0 = 0; k0 < SEQ; k0 += 16) {
    float4 av = *(const float4*)&Ph[(size_t)(m0 + ar) * SEQ + k0 + ac];
    float4 bv = *(const float4*)&Vh[(size_t)(k0 + br) * DH + bc];
    As[ac + 0][ar] = av.x; As[ac + 1][ar] = av.y;
    As[ac + 2][ar] = av.z; As[ac + 3][ar] = av.w;
    *(float4*)&Bs[br][bc] = bv;
    __syncthreads();
#pragma unroll
    for (int kk = 0; kk < 16; ++kk) {
      float a[4], bb[4];
#pragma unroll
      for (int i = 0; i < 4; ++i) a[i] = As[kk][ty * 4 + i];
#pragma unroll
      for (int j = 0; j < 4; ++j) bb[j] = Bs[kk][tx * 4 + j];
#pragma unroll
      for (int i = 0; i < 4; ++i)
#pragma unroll
        for (int j = 0; j < 4; ++j) acc[i][j] += a[i] * bb[j];
    }
    __syncthreads();
  }

#pragma unroll
  for (int i = 0; i < 4; ++i) {
    const int m = m0 + ty * 4 + i;  // seq position
#pragma unroll
    for (int j = 0; j < 4; ++j) {
      const int n = tx * 4 + j;  // dh (n0 == 0, DH == 64 == one tile)
      ctx[((size_t)(b * SEQ + m)) * D_MODEL + h * DH + n] = acc[i][j];
    }
  }
}

// ---------------------------------------------------------------------------
extern "C" void kernel_launch(void* const* d_in, const int* in_sizes, int n_in,
                              void* d_out, int out_size, void* d_ws, size_t ws_size,
                              hipStream_t stream) {
  (void)in_sizes; (void)n_in; (void)out_size; (void)ws_size;
  const float* q  = (const float*)d_in[0];
  const float* k  = (const float*)d_in[1];
  const float* v  = (const float*)d_in[2];
  const float* Wq = (const float*)d_in[3];
  const float* bq = (const float*)d_in[4];
  const float* Wk = (const float*)d_in[5];
  const float* bk = (const float*)d_in[6];
  const float* Wv = (const float*)d_in[7];
  const float* bv = (const float*)d_in[8];
  const float* Wo = (const float*)d_in[9];
  const float* bo = (const float*)d_in[10];

  float* out  = (float*)d_out;                       // [B,L,D]
  float* attn = out + (size_t)BL * D_MODEL;          // [B,H,L,L]

  // Workspace: qw, kw, vw (head layout [B,H,L,DH]) + ctx [B,L,D] = 134 MB fp32
  float* ws  = (float*)d_ws;
  float* qw  = ws;
  float* kw  = qw + (size_t)BL * D_MODEL;
  float* vw  = kw + (size_t)BL * D_MODEL;
  float* ctx = vw + (size_t)BL * D_MODEL;

  const dim3 blk(256);
  const dim3 gproj(D_MODEL / 64, BL / 64);           // (16,128)
  gemm_proj<1><<<gproj, blk, 0, stream>>>(q, Wq, bq, qw);
  gemm_proj<1><<<gproj, blk, 0, stream>>>(k, Wk, bk, kw);
  gemm_proj<1><<<gproj, blk, 0, stream>>>(v, Wv, bv, vw);

  const dim3 gs(SEQ / 64, SEQ / 64, BHEADS);         // (32,32,64)
  gemm_scores<<<gs, blk, 0, stream>>>(qw, kw, attn);

  softmax_rows<<<dim3(BHEADS * SEQ), blk, 0, stream>>>(attn);

  const dim3 gpv(SEQ / 64, BHEADS);                  // (32,64)
  gemm_pv<<<gpv, blk, 0, stream>>>(attn, vw, ctx);

  gemm_proj<0><<<gproj, blk, 0, stream>>>(ctx, Wo, bo, out);
}